// Round 5
// baseline (698.400 us; speedup 1.0000x reference)
//
#include <hip/hip_runtime.h>

#define B_TOT 2048
#define M_SEQ 64
#define SDIM 32
#define CDIM 8
#define LDIM 128
#define HDIM 512

#define NROWS_NEXT (B_TOT * M_SEQ)       // 131072
#define NROWS_ALL  (NROWS_NEXT + B_TOT)  // 133120

typedef short bf16x8 __attribute__((ext_vector_type(8)));
typedef float f32x16 __attribute__((ext_vector_type(16)));
typedef float f32x4v __attribute__((ext_vector_type(4)));   // clang vector: ok for nontemporal builtins

__device__ __forceinline__ unsigned short f2bf(float f) {
    unsigned int u = __builtin_bit_cast(unsigned int, f);
    u = u + 0x7FFFu + ((u >> 16) & 1u);   // round-to-nearest-even
    return (unsigned short)(u >> 16);
}

// h-buffer swizzle (bf16, 1024B rows): XOR bits 4-7 with row&15. Bijective,
// 16B-block preserving, applied to the FULL byte address by all readers/writers.
__device__ __forceinline__ unsigned swzh(unsigned b) { return b ^ (((b >> 10) & 15u) << 4); }
// fp32 staging tile swizzle (512B rows)
__device__ __forceinline__ unsigned swzf(unsigned b) { return b ^ (((b >> 9) & 15u) << 4); }

// ---------------------------------------------------------------------------
// Pack fp32 W[K][N] -> bf16 fragment-major for 32x32x16 MFMA B-operand:
// out[((kt*CT + ct)*64 + lane)*8 + j] = W[kt*16 + (lane>>5)*8 + j][ct*32 + (lane&31)]
// ---------------------------------------------------------------------------
__device__ __forceinline__ void pack_one(const float* __restrict__ W, short* __restrict__ out,
                                         int e, int N, int CT) {
    int j    = e & 7;
    int lane = (e >> 3) & 63;
    int tile = e >> 9;
    int ct   = tile % CT;
    int kt   = tile / CT;
    int k = kt * 16 + ((lane >> 5) << 3) + j;
    int n = (ct << 5) + (lane & 31);
    out[e] = (short)f2bf(W[(size_t)k * N + n]);
}

#define P_S0 16384
#define P_S1 (P_S0 + 262144)
#define P_S2 (P_S1 + 262144)
#define P_S3 (P_S2 + 65536)   // 606208 total

__global__ void pack_all(const float* __restrict__ w0, const float* __restrict__ w1,
                         const float* __restrict__ w2, const float* __restrict__ w3,
                         short* __restrict__ o0, short* __restrict__ o1,
                         short* __restrict__ o2, short* __restrict__ o3) {
    int id = blockIdx.x * 256 + threadIdx.x;
    if (id < P_S0)      pack_one(w0, o0, id, HDIM, 16);
    else if (id < P_S1) pack_one(w1, o1, id - P_S0, HDIM, 16);
    else if (id < P_S2) pack_one(w2, o2, id - P_S1, HDIM, 16);
    else if (id < P_S3) pack_one(w3, o3, id - P_S2, LDIM, 4);
}

// ---------------------------------------------------------------------------
// One 512-out MLP layer (32x32x16 MFMA), in-place in 64KB LDS h-buffer.
// 8 waves; wave w owns col-tiles {2w, 2w+1} x row-tiles {0,1}: acc 2x2xf32x16.
// A (LDS) and B (global, L2) both prefetched 1 kt ahead.
// ---------------------------------------------------------------------------
__device__ __forceinline__ void layer32(char* hbuf, const short* __restrict__ pb,
                                        const float* __restrict__ bias,
                                        int ktCount, int wave, int lane) {
    const int l31   = lane & 31;
    const int lhalf = lane >> 5;
    const unsigned base0 = (unsigned)(l31 * 1024 + (lhalf << 4));
    const unsigned xmask = ((unsigned)(lane & 15)) << 4;

    f32x16 acc[2][2];
    #pragma unroll
    for (int rt = 0; rt < 2; ++rt)
        #pragma unroll
        for (int ct = 0; ct < 2; ++ct)
            #pragma unroll
            for (int i = 0; i < 16; ++i) acc[rt][ct][i] = 0.f;

    const short* pB = pb + (wave * 2) * 512 + lane * 8;   // kt stride = 16*512 = 8192

    // prefetch kt=0
    bf16x8 a[2], b[2];
    {
        const char* ab = hbuf + (base0 ^ xmask);
        a[0] = *(const bf16x8*)(ab);
        a[1] = *(const bf16x8*)(ab + 32768);
        b[0] = *(const bf16x8*)(pB);
        b[1] = *(const bf16x8*)(pB + 512);
    }
    for (int kt = 0; kt < ktCount; ++kt) {
        const int ktn = (kt + 1 < ktCount) ? kt + 1 : kt;   // clamped (re-read last)
        bf16x8 an[2], bn[2];
        {
            const char* ab = hbuf + ((base0 + (unsigned)ktn * 32u) ^ xmask);
            an[0] = *(const bf16x8*)(ab);
            an[1] = *(const bf16x8*)(ab + 32768);
            const short* pn = pB + ktn * 8192;
            bn[0] = *(const bf16x8*)(pn);
            bn[1] = *(const bf16x8*)(pn + 512);
        }
        #pragma unroll
        for (int rt = 0; rt < 2; ++rt)
            #pragma unroll
            for (int ct = 0; ct < 2; ++ct)
                acc[rt][ct] = __builtin_amdgcn_mfma_f32_32x32x16_bf16(a[rt], b[ct], acc[rt][ct], 0, 0, 0);
        a[0] = an[0]; a[1] = an[1]; b[0] = bn[0]; b[1] = bn[1];
    }
    __syncthreads();   // all reads of hbuf done before in-place overwrite

    // epilogue: bias + relu + bf16, back into hbuf.
    // C/D layout (verified m74/m101): col=lane&31, row=(reg&3)+8*(reg>>2)+4*(lane>>5)
    #pragma unroll
    for (int ct = 0; ct < 2; ++ct) {
        int colg = (wave * 2 + ct) * 32 + l31;
        float bv = bias[colg];
        #pragma unroll
        for (int rt = 0; rt < 2; ++rt) {
            #pragma unroll
            for (int reg = 0; reg < 16; ++reg) {
                int row = rt * 32 + (reg & 3) + 8 * (reg >> 2) + 4 * lhalf;
                float v = fmaxf(acc[rt][ct][reg] + bv, 0.f);
                *(unsigned short*)(hbuf + swzh((unsigned)(row * 1024 + colg * 2))) = f2bf(v);
            }
        }
    }
    __syncthreads();
}

// ---------------------------------------------------------------------------
// Fused encoder: 64 rows/block. Blocks 0..2047 -> x_next, 2048..2079 -> x_k.
// ---------------------------------------------------------------------------
__global__ __launch_bounds__(512, 4) void encoder_kernel(
    const float* __restrict__ x_next, const float* __restrict__ x_k,
    const short* __restrict__ pw0, const short* __restrict__ pw1,
    const short* __restrict__ pw2, const short* __restrict__ pw3,
    const float* __restrict__ b0, const float* __restrict__ b1,
    const float* __restrict__ b2, const float* __restrict__ b3,
    float* __restrict__ z_target, float* __restrict__ z_k_out) {
    __shared__ __attribute__((aligned(16))) char hbuf[64 * 1024];
    const int tid   = threadIdx.x;
    const int wave  = tid >> 6;
    const int lane  = tid & 63;
    const int l31   = lane & 31;
    const int lhalf = lane >> 5;
    const int r0    = blockIdx.x * 64;

    const float* xin;
    float* zout;
    bool is_tgt = (r0 < NROWS_NEXT);
    if (is_tgt) {
        xin  = x_next + (size_t)r0 * SDIM;
        zout = z_target + (size_t)r0 * LDIM;
    } else {
        xin  = x_k + (size_t)(r0 - NROWS_NEXT) * SDIM;
        zout = z_k_out + (size_t)(r0 - NROWS_NEXT) * LDIM;
    }

    // stage 64x32 fp32 -> bf16 into h cols [0,32)
    {
        int row = tid >> 3;
        int c   = (tid & 7) * 4;
        float4 v = *(const float4*)(xin + row * SDIM + c);
        uint2 pk;
        pk.x = (unsigned int)f2bf(v.x) | ((unsigned int)f2bf(v.y) << 16);
        pk.y = (unsigned int)f2bf(v.z) | ((unsigned int)f2bf(v.w) << 16);
        *(uint2*)(hbuf + swzh((unsigned)(row * 1024 + c * 2))) = pk;
    }
    __syncthreads();

    layer32(hbuf, pw0, b0, 2, wave, lane);    // 32  -> 512, relu (K=32 -> 2 kt)
    layer32(hbuf, pw1, b1, 32, wave, lane);   // 512 -> 512, relu
    layer32(hbuf, pw2, b2, 32, wave, lane);   // 512 -> 512, relu

    // layer 3: 512 -> 128, no relu. Wave w: col-tile w&3, row-tile w>>2 (acc 16).
    {
        const int ct  = wave & 3;
        const int rtb = (wave >> 2) * 32;
        const unsigned base0 = (unsigned)(l31 * 1024 + (lhalf << 4)) + (unsigned)(rtb * 1024);
        const unsigned xmask = ((unsigned)(lane & 15)) << 4;
        f32x16 acc;
        #pragma unroll
        for (int i = 0; i < 16; ++i) acc[i] = 0.f;

        const short* pB = pw3 + ct * 512 + lane * 8;    // kt stride = 4*512 = 2048
        bf16x8 a = *(const bf16x8*)(hbuf + (base0 ^ xmask));
        bf16x8 b = *(const bf16x8*)(pB);
        for (int kt = 0; kt < 32; ++kt) {
            const int ktn = (kt < 31) ? kt + 1 : kt;
            bf16x8 an = *(const bf16x8*)(hbuf + ((base0 + (unsigned)ktn * 32u) ^ xmask));
            bf16x8 bn = *(const bf16x8*)(pB + ktn * 2048);
            acc = __builtin_amdgcn_mfma_f32_32x32x16_bf16(a, b, acc, 0, 0, 0);
            a = an; b = bn;
        }
        __syncthreads();   // done reading bf16 h; reuse hbuf as fp32 [64][128]

        int colg = ct * 32 + l31;
        float bv = b3[colg];
        #pragma unroll
        for (int reg = 0; reg < 16; ++reg) {
            int row = rtb + (reg & 3) + 8 * (reg >> 2) + 4 * lhalf;
            *(float*)(hbuf + swzf((unsigned)(row * 512 + colg * 4))) = acc[reg] + bv;
        }
        __syncthreads();

        #pragma unroll
        for (int pass = 0; pass < 4; ++pass) {
            unsigned L = (unsigned)(pass * 512 + tid) * 16;
            f32x4v v = *(const f32x4v*)(hbuf + swzf(L));
            if (is_tgt) __builtin_nontemporal_store(v, (f32x4v*)(zout + (L >> 2)));
            else        *(f32x4v*)(zout + (L >> 2)) = v;
        }
    }
}

// ---------------------------------------------------------------------------
// Recurrence z_m = z_{m-1} @ A_w + u[:,m,:] @ B_w, fp32 exact.
// 256 blocks x 512 threads, 8 batch rows/block. Thread t: out-col t&127,
// rows {t>>7, (t>>7)+4}; holds A_w[:, col] in 128 VGPRs -> full 128-dot,
// z broadcast-read from LDS; double-buffered z -> ONE barrier per step.
// ---------------------------------------------------------------------------
#define RR 8
__global__ __launch_bounds__(512, 3) void recurrence_kernel(
    const float* __restrict__ zk, const float* __restrict__ u,
    const float* __restrict__ Bw, const float* __restrict__ Aw,
    float* __restrict__ zpred) {
    __shared__ float zbuf[2][RR][136];   // 136-f stride: rows land in distinct banks
    __shared__ float u_lds[RR * M_SEQ * CDIM];   // [b][m][c]
    __shared__ float Bw_lds[CDIM * 128];
    const int tid = threadIdx.x;
    const int col = tid & 127;
    const int rg  = tid >> 7;            // 0..3 -> rows rg, rg+4
    const int b0  = blockIdx.x * RR;

    float a[128];
    #pragma unroll
    for (int k = 0; k < 128; ++k) a[k] = Aw[(size_t)k * 128 + col];

    for (int id = tid; id < RR * 128; id += 512)
        zbuf[0][id >> 7][id & 127] = zk[(size_t)(b0 + (id >> 7)) * 128 + (id & 127)];
    for (int id = tid; id < RR * M_SEQ * CDIM; id += 512)
        u_lds[id] = u[(size_t)b0 * M_SEQ * CDIM + id];
    for (int id = tid; id < CDIM * 128; id += 512) Bw_lds[id] = Bw[id];
    __syncthreads();

    int s = 0;
    for (int m = 0; m < M_SEQ; ++m) {
        const float* z0 = &zbuf[s][rg][0];
        const float* z1 = &zbuf[s][rg + 4][0];
        float v0 = 0.f, v1 = 0.f;
        #pragma unroll
        for (int kk = 0; kk < 32; ++kk) {
            float4 za = *(const float4*)(z0 + kk * 4);   // same addr across lanes: broadcast
            float4 zb = *(const float4*)(z1 + kk * 4);
            v0 += a[kk*4+0]*za.x + a[kk*4+1]*za.y + a[kk*4+2]*za.z + a[kk*4+3]*za.w;
            v1 += a[kk*4+0]*zb.x + a[kk*4+1]*zb.y + a[kk*4+2]*zb.z + a[kk*4+3]*zb.w;
        }
        #pragma unroll
        for (int c = 0; c < CDIM; ++c) {
            float bw = Bw_lds[c * 128 + col];
            v0 += u_lds[rg * (M_SEQ*CDIM) + m * CDIM + c] * bw;
            v1 += u_lds[(rg + 4) * (M_SEQ*CDIM) + m * CDIM + c] * bw;
        }
        zbuf[s ^ 1][rg][col] = v0;
        zbuf[s ^ 1][rg + 4][col] = v1;
        zpred[((size_t)(b0 + rg) * M_SEQ + m) * 128 + col] = v0;
        zpred[((size_t)(b0 + rg + 4) * M_SEQ + m) * 128 + col] = v1;
        __syncthreads();
        s ^= 1;
    }
}

// ---------------------------------------------------------------------------
// Decoder x_pred = z_pred @ C_w + C_b. 64 rows/block (2048 blocks) so C_w is
// staged once per 64 rows (32MB total L2 traffic, was 256MB at 8 rows/block).
// ---------------------------------------------------------------------------
__global__ __launch_bounds__(256) void decoder_kernel(
    const float* __restrict__ zpred, const float* __restrict__ Cw,
    const float* __restrict__ Cb, float* __restrict__ xpred) {
    __shared__ float C_lds[LDIM * SDIM];
    __shared__ float cb_lds[SDIM];
    const int tid = threadIdx.x;
    for (int id = tid; id < LDIM * SDIM; id += 256) C_lds[id] = Cw[id];
    if (tid < SDIM) cb_lds[tid] = Cb[tid];
    __syncthreads();

    const int col = tid & 31;
    const int r8  = tid >> 5;                      // 0..7
    const size_t rows0 = (size_t)blockIdx.x * 64;
    #pragma unroll
    for (int p = 0; p < 8; ++p) {
        size_t row = rows0 + p * 8 + r8;
        const float4* z4 = (const float4*)(zpred + row * LDIM);
        float s = cb_lds[col];
        #pragma unroll
        for (int i = 0; i < 32; ++i) {
            float4 zv = z4[i];
            s += zv.x * C_lds[(i*4+0)*SDIM + col] + zv.y * C_lds[(i*4+1)*SDIM + col] +
                 zv.z * C_lds[(i*4+2)*SDIM + col] + zv.w * C_lds[(i*4+3)*SDIM + col];
        }
        __builtin_nontemporal_store(s, xpred + row * SDIM + col);
    }
}

extern "C" void kernel_launch(void* const* d_in, const int* in_sizes, int n_in,
                              void* d_out, int out_size, void* d_ws, size_t ws_size,
                              hipStream_t stream) {
    const float* x_k    = (const float*)d_in[0];
    const float* u_seq  = (const float*)d_in[1];
    const float* x_next = (const float*)d_in[2];
    const float* w0 = (const float*)d_in[3];  const float* b0 = (const float*)d_in[4];
    const float* w1 = (const float*)d_in[5];  const float* b1 = (const float*)d_in[6];
    const float* w2 = (const float*)d_in[7];  const float* b2 = (const float*)d_in[8];
    const float* w3 = (const float*)d_in[9];  const float* b3 = (const float*)d_in[10];
    const float* A_w = (const float*)d_in[11];
    const float* B_w = (const float*)d_in[12];
    const float* C_w = (const float*)d_in[13];
    const float* C_b = (const float*)d_in[14];

    float* out    = (float*)d_out;
    float* z_pred = out;                                   // 2048*64*128
    float* x_pred = out + (size_t)NROWS_NEXT * LDIM;       // 2048*64*32
    float* z_tgt  = x_pred + (size_t)NROWS_NEXT * SDIM;    // 2048*64*128

    char* ws = (char*)d_ws;
    short* pw0 = (short*)(ws);                             // 32 KB
    short* pw1 = (short*)(ws + 32768);                     // 512 KB
    short* pw2 = (short*)(ws + 32768 + 524288);            // 512 KB
    short* pw3 = (short*)(ws + 32768 + 2 * 524288);        // 128 KB
    float* z_k_buf = (float*)(ws + 32768 + 2 * 524288 + 131072);  // 1 MB

    pack_all<<<(P_S3 + 255) / 256, 256, 0, stream>>>(w0, w1, w2, w3, pw0, pw1, pw2, pw3);

    encoder_kernel<<<NROWS_ALL / 64, 512, 0, stream>>>(
        x_next, x_k, pw0, pw1, pw2, pw3, b0, b1, b2, b3, z_tgt, z_k_buf);

    recurrence_kernel<<<B_TOT / RR, 512, 0, stream>>>(z_k_buf, u_seq, B_w, A_w, z_pred);

    decoder_kernel<<<NROWS_NEXT / 64, 256, 0, stream>>>(z_pred, C_w, C_b, x_pred);
}